// Round 16
// baseline (183.899 us; speedup 1.0000x reference)
//
#include <hip/hip_runtime.h>
#include <hip/hip_bf16.h>
#include <math.h>

// Problem constants (B=2, L=1024, d_model=512, d_inner=1024, H=8, N=16, hd=128,
// dt_rank=32, out_dim=560). T = B*L = 2048 tokens.
//
// Pipeline (GEMMs in bf16 MFMA, scan math f32):
//  0) cvt_all: x,W_in,W_x,W_out -> bf16 + W_dt transpose + AA table
//     (AA[h*16+n] = {-exp(A_log)*log2e, A_imag/(2pi)}, 1KB, lives past scan)
//  1) gemm_bf16_128: xz[T,2048] = x_bf @ Win_bf^T        (f32 out)
//  2) conv_silu: dx[t,c].y = silu(dwconv(xz[:,:1024])), xc_bf (bf16 copy),
//     in-place silu on the z-half: xz[t,1024+c] = silu(xz[t,1024+c])
//  3) gemm_bf16_64: proj[T,560] = xc_bf @ Wx_bf^T
//  4) pack2: dx[t,c].x = softplus(proj[:, :32] . W_dtT + b_dt);
//            scanin[t,h,n]={Br,Bi,Cr,Ci}; gates[t,h]={1-lg, lg*eg}
//  5) split-carry chunked scan (chunk=64):
//     part1 (heavy, ONCE): zero-carry scan, TWO channels (n, n+8) PER THREAD
//        (ILP-2: shared dx/gates/S/addressing; breaks the serial-FMA +
//        load-latency stall -- proven R13, 69 -> ~45 us).  y-reduce via
//        __shfl_xor 1,2,4 butterfly.  Stores yd[t,c] (into xz x-half),
//        S[t,c]=cum delta sum, csum={h_end} for both n.
//     part2: carry scan over chunks; A_chunk = exp2(S64*Are2)*cis(S64*AimR);
//        writes hstart IN-PLACE over csum.  (unchanged, proven R10)
//     part3: ONE THREAD PER OUTPUT (t,c), inner n-loop over 16 states.
//        No recurrence, no cross-lane ops, no redundant broadcast loads, no
//        divergent store.  (R14 lesson: ILP-2 is for dependency-bound loops;
//        part3 is trans-throughput bound -- so strip structural overhead.)
//        corr = sum_n mag*(co*u+sn*v); out = (yd+corr)*gz -> yg_bf.
//  6) gemm_bf16_64: out[T,512] = yg_bf @ Wout_bf^T

typedef __attribute__((ext_vector_type(8))) short bf16x8;
typedef __attribute__((ext_vector_type(4))) float f32x4;

#if __has_builtin(__builtin_amdgcn_exp2f)
__device__ __forceinline__ float fexp2(float x) { return __builtin_amdgcn_exp2f(x); }
#else
__device__ __forceinline__ float fexp2(float x) {
  float r; asm("v_exp_f32 %0, %1\n\ts_nop 1" : "=v"(r) : "v"(x)); return r;
}
#endif
#if __has_builtin(__builtin_amdgcn_sinf)
__device__ __forceinline__ float fsin_rev(float x) { return __builtin_amdgcn_sinf(x); }
#else
__device__ __forceinline__ float fsin_rev(float x) {
  float r; asm("v_sin_f32 %0, %1\n\ts_nop 1" : "=v"(r) : "v"(x)); return r;
}
#endif
#if __has_builtin(__builtin_amdgcn_cosf)
__device__ __forceinline__ float fcos_rev(float x) { return __builtin_amdgcn_cosf(x); }
#else
__device__ __forceinline__ float fcos_rev(float x) {
  float r; asm("v_cos_f32 %0, %1\n\ts_nop 1" : "=v"(r) : "v"(x)); return r;
}
#endif

__device__ __forceinline__ short f2bf(float f) {  // round-to-nearest-even
  unsigned u = __float_as_uint(f);
  return (short)((u + 0x7FFFu + ((u >> 16) & 1u)) >> 16);
}

// ---------------------------------------------------------------------------
// Fused f32->bf16 conversion of x, W_in, W_x, W_out (float4 granules) plus
// W_dt transpose plus AA table.  Grid 3249*256 = 831744 (guarded; work =
// 798720 cvt + 32768 wdtT + 128 AA = 831616).
// ---------------------------------------------------------------------------
__global__ __launch_bounds__(256)
void cvt_all_k(const float* __restrict__ x, const float* __restrict__ W_in,
               const float* __restrict__ W_x, const float* __restrict__ W_out,
               const float* __restrict__ W_dt, const float* __restrict__ A_log,
               const float* __restrict__ A_imag,
               short* __restrict__ x_bf, short* __restrict__ win_bf,
               short* __restrict__ wx_bf, short* __restrict__ wout_bf,
               float* __restrict__ W_dtT, float2* __restrict__ AA) {
  const int i = blockIdx.x * 256 + threadIdx.x;
  if (i < 798720) {
    const float4* src; short4* dst; int off;
    if (i < 262144)      { src = (const float4*)x;     dst = (short4*)x_bf;    off = i; }
    else if (i < 524288) { src = (const float4*)W_in;  dst = (short4*)win_bf;  off = i - 262144; }
    else if (i < 667648) { src = (const float4*)W_x;   dst = (short4*)wx_bf;   off = i - 524288; }
    else                 { src = (const float4*)W_out; dst = (short4*)wout_bf; off = i - 667648; }
    const float4 v = src[off];
    short4 o;
    o.x = f2bf(v.x); o.y = f2bf(v.y); o.z = f2bf(v.z); o.w = f2bf(v.w);
    dst[off] = o;
  } else if (i < 831488) {
    const int j = i - 798720;  // 0..32767: W_dtT[r*1024+c] = W_dt[c*32+r]
    W_dtT[j] = W_dt[(j & 1023) * 32 + (j >> 10)];
  } else if (i < 831616) {
    const int j = i - 831488;  // 0..127: per-(h,n) scan constants
    AA[j] = make_float2(-__expf(A_log[j]) * 1.44269504f,
                        A_imag[j] * 0.15915494f);
  }
}

// ---------------------------------------------------------------------------
// bf16 MFMA GEMM (NT), 128x128 tile / 256 threads (4 waves x 64x64 quadrant).
// ---------------------------------------------------------------------------
__global__ __launch_bounds__(256)
void gemm_bf16_128(const short* __restrict__ A, const short* __restrict__ W,
                   float* __restrict__ C, int N, int K) {
  __shared__ short As[128][40];
  __shared__ short Ws[128][40];
  const int tid  = threadIdx.x;
  const int m0   = blockIdx.y * 128;
  const int n0   = blockIdx.x * 128;
  const int lane = tid & 63;
  const int wid  = tid >> 6;
  const int wm   = (wid >> 1) * 64;
  const int wn   = (wid & 1) * 64;
  const int r0   = tid >> 2;
  const int q    = (tid & 3) * 8;
  const int lrow = lane & 15;
  const int lk   = (lane >> 4) * 8;

  f32x4 acc[4][4] = {};

  for (int k0 = 0; k0 < K; k0 += 32) {
    const size_t abase = (size_t)(m0 + r0) * K + k0 + q;
    const uint4 a0v = *reinterpret_cast<const uint4*>(A + abase);
    const uint4 a1v = *reinterpret_cast<const uint4*>(A + abase + (size_t)64 * K);
    const int wr0 = n0 + r0, wr1 = wr0 + 64;
    uint4 w0v = make_uint4(0, 0, 0, 0), w1v = make_uint4(0, 0, 0, 0);
    if (wr0 < N) w0v = *reinterpret_cast<const uint4*>(W + (size_t)wr0 * K + k0 + q);
    if (wr1 < N) w1v = *reinterpret_cast<const uint4*>(W + (size_t)wr1 * K + k0 + q);

    __syncthreads();
    *reinterpret_cast<uint4*>(&As[r0][q])      = a0v;
    *reinterpret_cast<uint4*>(&As[r0 + 64][q]) = a1v;
    *reinterpret_cast<uint4*>(&Ws[r0][q])      = w0v;
    *reinterpret_cast<uint4*>(&Ws[r0 + 64][q]) = w1v;
    __syncthreads();

    bf16x8 af[4], bfr[4];
#pragma unroll
    for (int i = 0; i < 4; ++i)
      af[i] = *reinterpret_cast<const bf16x8*>(&As[wm + i * 16 + lrow][lk]);
#pragma unroll
    for (int j = 0; j < 4; ++j)
      bfr[j] = *reinterpret_cast<const bf16x8*>(&Ws[wn + j * 16 + lrow][lk]);
#pragma unroll
    for (int i = 0; i < 4; ++i)
#pragma unroll
      for (int j = 0; j < 4; ++j)
        acc[i][j] = __builtin_amdgcn_mfma_f32_16x16x32_bf16(af[i], bfr[j],
                                                            acc[i][j], 0, 0, 0);
  }

  const int crow = (lane >> 4) * 4;
  const int ccol = lane & 15;
#pragma unroll
  for (int i = 0; i < 4; ++i) {
#pragma unroll
    for (int j = 0; j < 4; ++j) {
      const int col = n0 + wn + j * 16 + ccol;
      if (col < N) {
        const int row = m0 + wm + i * 16 + crow;
#pragma unroll
        for (int r = 0; r < 4; ++r)
          C[(size_t)(row + r) * N + col] = acc[i][j][r];
      }
    }
  }
}

// ---------------------------------------------------------------------------
// bf16 MFMA GEMM (NT), 64x64 tile / 256 threads (4 waves x 32x32 quadrant).
// ---------------------------------------------------------------------------
__global__ __launch_bounds__(256)
void gemm_bf16_64(const short* __restrict__ A, const short* __restrict__ W,
                  float* __restrict__ C, int N, int K) {
  __shared__ short As[64][40];
  __shared__ short Ws[64][40];
  const int tid  = threadIdx.x;
  const int m0   = blockIdx.y * 64;
  const int n0   = blockIdx.x * 64;
  const int lane = tid & 63;
  const int wid  = tid >> 6;
  const int wm   = (wid >> 1) * 32;
  const int wn   = (wid & 1) * 32;
  const int r0   = tid >> 2;
  const int q    = (tid & 3) * 8;
  const int lrow = lane & 15;
  const int lk   = (lane >> 4) * 8;

  f32x4 acc[2][2] = {};

  for (int k0 = 0; k0 < K; k0 += 32) {
    const uint4 a0v =
        *reinterpret_cast<const uint4*>(A + (size_t)(m0 + r0) * K + k0 + q);
    const int wr0 = n0 + r0;
    uint4 w0v = make_uint4(0, 0, 0, 0);
    if (wr0 < N) w0v = *reinterpret_cast<const uint4*>(W + (size_t)wr0 * K + k0 + q);

    __syncthreads();
    *reinterpret_cast<uint4*>(&As[r0][q]) = a0v;
    *reinterpret_cast<uint4*>(&Ws[r0][q]) = w0v;
    __syncthreads();

    bf16x8 af[2], bfr[2];
#pragma unroll
    for (int i = 0; i < 2; ++i)
      af[i] = *reinterpret_cast<const bf16x8*>(&As[wm + i * 16 + lrow][lk]);
#pragma unroll
    for (int j = 0; j < 2; ++j)
      bfr[j] = *reinterpret_cast<const bf16x8*>(&Ws[wn + j * 16 + lrow][lk]);
#pragma unroll
    for (int i = 0; i < 2; ++i)
#pragma unroll
      for (int j = 0; j < 2; ++j)
        acc[i][j] = __builtin_amdgcn_mfma_f32_16x16x32_bf16(af[i], bfr[j],
                                                            acc[i][j], 0, 0, 0);
  }

  const int crow = (lane >> 4) * 4;
  const int ccol = lane & 15;
#pragma unroll
  for (int i = 0; i < 2; ++i) {
#pragma unroll
    for (int j = 0; j < 2; ++j) {
      const int col = n0 + wn + j * 16 + ccol;
      if (col < N) {
        const int row = m0 + wm + i * 16 + crow;
#pragma unroll
        for (int r = 0; r < 4; ++r)
          C[(size_t)(row + r) * N + col] = acc[i][j][r];
      }
    }
  }
}

// ---------------------------------------------------------------------------
// Causal depthwise conv (K=3) + silu; writes dx.y (f32) and xc_bf (bf16).
// Also applies silu IN-PLACE to the z half: xz[t,1024+c] = silu(...).
// ---------------------------------------------------------------------------
__global__ __launch_bounds__(256)
void conv_silu_k(float* __restrict__ xz, const float* __restrict__ conv_w,
                 const float* __restrict__ conv_b, float* __restrict__ dxf,
                 short* __restrict__ xcb) {
  const int idx = blockIdx.x * 256 + threadIdx.x;
  const int c = idx & 1023;
  const int t = idx >> 10;
  const int l = t & 1023;
  const float* xp = xz + (size_t)t * 2048 + c;
  float acc = conv_b[c];
  const float w0 = conv_w[c * 3 + 0];
  const float w1 = conv_w[c * 3 + 1];
  const float w2 = conv_w[c * 3 + 2];
  acc += w2 * xp[0];
  if (l >= 1) acc += w1 * xp[-2048];
  if (l >= 2) acc += w0 * xp[-2 * 2048];
  const float v = acc / (1.f + __expf(-acc));
  dxf[2 * (size_t)idx + 1] = v;
  xcb[idx] = f2bf(v);
  // in-place silu on z
  float* zp = xz + (size_t)t * 2048 + 1024 + c;
  const float zv = *zp;
  *zp = zv / (1.f + __expf(-zv));
}

// ---------------------------------------------------------------------------
// pack2: fused delta + scanin-pack + gates.
// ---------------------------------------------------------------------------
__global__ __launch_bounds__(256)
void pack2_k(const float* __restrict__ proj, const float* __restrict__ W_dtT,
             const float* __restrict__ b_dt, float* __restrict__ dxf,
             float4* __restrict__ scanin, float2* __restrict__ gates) {
  const int idx = blockIdx.x * 256 + threadIdx.x;  // 2097152 + 262144
  if (idx < 2097152) {
    const int c = idx & 1023;
    const int t = idx >> 10;
    const float* pr = proj + (size_t)t * 560;
    float acc = b_dt[c];
#pragma unroll
    for (int r = 0; r < 32; ++r) acc = fmaf(pr[r], W_dtT[r * 1024 + c], acc);
    dxf[2 * (size_t)idx] = fmaxf(acc, 0.f) + log1pf(__expf(-fabsf(acc)));
  } else {
    const int j = idx - 2097152;
    const int n = j & 15;
    const int h = (j >> 4) & 7;
    const int t = j >> 7;
    const float* pr = proj + (size_t)t * 560;
    const int hn = h * 16 + n;
    scanin[j] = make_float4(pr[32 + hn], pr[160 + hn], pr[288 + hn], pr[416 + hn]);
    if (n == 0) {
      const float lg = 1.f / (1.f + __expf(-pr[544 + h]));
      const float eg = 1.f / (1.f + __expf(-pr[552 + h]));
      gates[t * 8 + h] = make_float2(1.f - lg, lg * eg);
    }
  }
}

// ---------------------------------------------------------------------------
// Split-carry chunked scan, part1 with 2 channels (n, n+8) per thread.
// gid bits: [b:1][ck:4][h:3][d:7][n:3] -> 262144 threads (1024 blocks).
// y-reduce: __shfl_xor 1,2,4 butterfly (direction-free, group-closed).
// ---------------------------------------------------------------------------
__global__ __launch_bounds__(256)
void scan_part1_k(float* __restrict__ pyd,        // xz base (x-half, yd out)
                  const float2* __restrict__ dx,
                  const float4* __restrict__ scanin,
                  const float2* __restrict__ gates,
                  const float* __restrict__ A_log, const float* __restrict__ A_imag,
                  const float* __restrict__ D_param,
                  float* __restrict__ Ssum, float2* __restrict__ csum) {
  const int gid = blockIdx.x * 256 + threadIdx.x;  // 262144 total
  const int n  = gid & 7;            // this thread handles n and n+8
  const int d  = (gid >> 3) & 127;
  const int h  = (gid >> 10) & 7;
  const int ck = (gid >> 13) & 15;
  const int b  = gid >> 17;
  const int c  = h * 128 + d;

  const float Are2a = -__expf(A_log[h * 16 + n])     * 1.44269504f;
  const float AimRa =  A_imag[h * 16 + n]            * 0.15915494f;
  const float Are2b = -__expf(A_log[h * 16 + n + 8]) * 1.44269504f;
  const float AimRb =  A_imag[h * 16 + n + 8]        * 0.15915494f;
  const float Dc   = D_param[c];
  const int t0 = b * 1024 + ck * 64;

  float bxpra = 0.f, bxpia = 0.f, bxprb = 0.f, bxpib = 0.f;
  if (ck > 0) {
    const float xv = dx[(size_t)(t0 - 1) * 1024 + c].y;
    const float2 bpa =
        *reinterpret_cast<const float2*>(&scanin[(size_t)(t0 - 1) * 128 + h * 16 + n]);
    const float2 bpb =
        *reinterpret_cast<const float2*>(&scanin[(size_t)(t0 - 1) * 128 + h * 16 + n + 8]);
    bxpra = xv * bpa.x; bxpia = xv * bpa.y;
    bxprb = xv * bpb.x; bxpib = xv * bpb.y;
  }

  // 32-bit byte offsets from uniform bases
  unsigned odx = ((unsigned)t0 * 1024u + (unsigned)c) * 8u;
  unsigned osc = ((unsigned)t0 * 128u + (unsigned)(h * 16 + n)) * 16u;  // +128B for n+8
  unsigned ogt = ((unsigned)t0 * 8u + (unsigned)h) * 8u;
  unsigned opy = ((unsigned)t0 * 2048u + (unsigned)c) * 4u;
  unsigned oss = ((unsigned)t0 * 1024u + (unsigned)c) * 4u;

  float S = 0.f;
  float hra = 0.f, hia = 0.f, hrb = 0.f, hib = 0.f;
#pragma unroll 4
  for (int l = 0; l < 64; ++l) {
    const float2 dxv = *(const float2*)((const char*)dx + odx);
    const float4 bca = *(const float4*)((const char*)scanin + osc);
    const float4 bcb = *(const float4*)((const char*)scanin + osc + 128u);
    const float2 bg  = *(const float2*)((const char*)gates + ogt);

    const float dv = dxv.x, xv = dxv.y;
    const float betas = dv * bg.x;
    const float gam   = dv * bg.y;
    S += dv;

    // channel A (state index n)
    {
      const float mag = fexp2(dv * Are2a);
      const float rev = dv * AimRa;
      const float sn = fsin_rev(rev), co = fcos_rev(rev);
      const float are = mag * co, aim = mag * sn;
      const float bxr = xv * bca.x, bxi = xv * bca.y;
      const float tr = fmaf(betas, bxpra, hra);
      const float ti = fmaf(betas, bxpia, hia);
      hra = fmaf(are, tr, fmaf(-aim, ti, gam * bxr));
      hia = fmaf(are, ti, fmaf(aim, tr, gam * bxi));
      bxpra = bxr; bxpia = bxi;
    }
    // channel B (state index n+8)
    {
      const float mag = fexp2(dv * Are2b);
      const float rev = dv * AimRb;
      const float sn = fsin_rev(rev), co = fcos_rev(rev);
      const float are = mag * co, aim = mag * sn;
      const float bxr = xv * bcb.x, bxi = xv * bcb.y;
      const float tr = fmaf(betas, bxprb, hrb);
      const float ti = fmaf(betas, bxpib, hib);
      hrb = fmaf(are, tr, fmaf(-aim, ti, gam * bxr));
      hib = fmaf(are, ti, fmaf(aim, tr, gam * bxi));
      bxprb = bxr; bxpib = bxi;
    }

    float y = fmaf(hra, bca.z, hia * bca.w) + fmaf(hrb, bcb.z, hib * bcb.w);
    y += __shfl_xor(y, 1);   // butterfly: direction-free, stays in 8-group
    y += __shfl_xor(y, 2);
    y += __shfl_xor(y, 4);

    if (n == 0) {
      *(float*)((char*)pyd + opy)  = fmaf(Dc, xv, y);  // yd (ungated)
      *(float*)((char*)Ssum + oss) = S;
    }
    odx += 8192u; osc += 2048u; ogt += 64u; opy += 8192u; oss += 4096u;
  }
  const int sbase = (((b * 16 + ck) * 8 + h) << 11) + d * 16 + n;
  csum[sbase]     = make_float2(hra, hia);
  csum[sbase + 8] = make_float2(hrb, hib);
}

// ---------------------------------------------------------------------------
// part2: carry scan over 16 chunk summaries; A_chunk from S64 (shared-A
// cumulative-product identity).  hstart written IN-PLACE over csum.
// ---------------------------------------------------------------------------
__global__ __launch_bounds__(256)
void scan_part2_k(const float* __restrict__ Ssum, const float* __restrict__ A_log,
                  const float* __restrict__ A_imag, float2* __restrict__ csum) {
  const int gid = blockIdx.x * 256 + threadIdx.x;  // 32768 total
  const int low = gid & 2047;                      // d*16+n
  const int h   = (gid >> 11) & 7;
  const int b   = gid >> 14;
  const int n   = low & 15;
  const int c   = h * 128 + (low >> 4);
  const float Are2 = -__expf(A_log[h * 16 + n]) * 1.44269504f;
  const float AimR = A_imag[h * 16 + n] * 0.15915494f;
  float hr = 0.f, hi = 0.f;  // carry
#pragma unroll
  for (int ck = 0; ck < 16; ++ck) {
    const int s = (((b * 16 + ck) * 8 + h) << 11) + low;
    const float2 he = csum[s];
    const float S64 = Ssum[(size_t)(b * 1024 + ck * 64 + 63) * 1024 + c];
    csum[s] = make_float2(hr, hi);  // hstart for this chunk
    const float mag = fexp2(S64 * Are2);
    const float rev = S64 * AimR;
    const float sn = fsin_rev(rev), co = fcos_rev(rev);
    const float ar = mag * co, ai = mag * sn;
    const float nhr = fmaf(ar, hr, fmaf(-ai, hi, he.x));
    const float nhi = fmaf(ar, hi, fmaf(ai, hr, he.y));
    hr = nhr; hi = nhi;
  }
}

// ---------------------------------------------------------------------------
// part3: one thread per output (t,c); inner n-loop over 16 states.
//   corr = sum_n mag_n*(co_n*u_n + sn_n*v_n),  u=Cr*hcr+Ci*hci,
//   v=Ci*hcr-Cr*hci;  out[t,c] = (yd + corr) * gz.
// No cross-lane ops, no broadcast-redundant loads, no divergent store.
// AA table gives per-(h,n) {Are2, AimR} (precomputed in cvt_all_k).
// Grid: 8192 blocks x 256 = 2,097,152 threads (full occupancy).
// ---------------------------------------------------------------------------
__global__ __launch_bounds__(256)
void scan_part3_k(const float* __restrict__ gz, const float* __restrict__ pyd,
                  const float* __restrict__ Ssum, const float4* __restrict__ scanin,
                  const float2* __restrict__ AA, const float2* __restrict__ hstart,
                  short* __restrict__ ygb) {
  const int gid = blockIdx.x * 256 + threadIdx.x;  // 2,097,152
  const int c  = gid & 1023;
  const int t  = gid >> 10;
  const int h  = c >> 7;
  const int d  = c & 127;
  const int b  = t >> 10;
  const int ck = (t >> 6) & 15;

  const float S   = Ssum[(size_t)t * 1024 + c];
  const float ydv = pyd[(size_t)t * 2048 + c];
  const float gzv = gz[(size_t)t * 2048 + 1024 + c];

  const float2* hc = hstart + ((((b * 16 + ck) * 8 + h) << 11) + d * 16);
  const float2* cv = reinterpret_cast<const float2*>(scanin + (size_t)t * 128 + h * 16);
  const float2* aa = AA + h * 16;

  float corr = 0.f;
#pragma unroll 4
  for (int n = 0; n < 16; ++n) {
    const float2 a   = aa[n];
    const float2 hcv = hc[n];
    const float2 cvv = cv[2 * n + 1];  // {Cr, Ci} of scanin[t,h,n]
    const float mag = fexp2(S * a.x);
    const float rev = S * a.y;
    const float sn = fsin_rev(rev), co = fcos_rev(rev);
    const float u = fmaf(cvv.x, hcv.x, cvv.y * hcv.y);
    const float v = fmaf(cvv.y, hcv.x, -cvv.x * hcv.y);
    corr = fmaf(mag, fmaf(co, u, sn * v), corr);
  }
  ygb[(size_t)t * 1024 + c] = f2bf((ydv + corr) * gzv);
}

// ---------------------------------------------------------------------------
extern "C" void kernel_launch(void* const* d_in, const int* in_sizes, int n_in,
                              void* d_out, int out_size, void* d_ws, size_t ws_size,
                              hipStream_t stream) {
  (void)in_sizes; (void)n_in; (void)out_size; (void)ws_size;
  const float* x       = (const float*)d_in[0];
  const float* W_in    = (const float*)d_in[1];
  const float* conv_w  = (const float*)d_in[2];
  const float* conv_b  = (const float*)d_in[3];
  const float* W_x     = (const float*)d_in[4];
  const float* W_dt    = (const float*)d_in[5];
  const float* b_dt    = (const float*)d_in[6];
  const float* A_log   = (const float*)d_in[7];
  const float* A_imag  = (const float*)d_in[8];
  const float* D_param = (const float*)d_in[9];
  const float* W_out   = (const float*)d_in[10];
  float* out = (float*)d_out;

  // workspace layout (float offsets); total 15,106,304 floats = 57.63 MiB.
  // xz x-half (cols 0-1023) is dead after conv_silu -> part1 stores yd there.
  // csum (float2) doubles as hstart (part2 rewrites in place).
  // Aliases live inside csum+Ssum's slot [11960320, 15106048); all are dead
  // before part1 writes csum/Ssum.  AA lives PAST the scan -> outside slot.
  //   x_bf   [11960320, 12484608)   1,048,576 shorts
  //   win_bf [12484608, 13008896)   1,048,576 shorts
  //   xc_bf  [13008896, 14057472)   2,097,152 shorts
  //   wx_bf  [14057472, 14344192)     573,440 shorts
  //   wdtT   [14344192, 14376960)      32,768 floats
  //   AA     [15106048, 15106304)     128 float2 (NOT aliased)
  float* ws = (float*)d_ws;
  float*  xz      = ws;                          // 4,194,304 (yd aliases x-half)
  float*  proj    = ws + 4194304;                // 1,146,880
  float2* dx      = (float2*)(ws + 5341184);     // 4,194,304 (2M float2)
  float4* scanin  = (float4*)(ws + 9535488);     // 1,048,576
  float2* gates   = (float2*)(ws + 10584064);    //    65,536
  short*  yg_bf   = (short*)(ws + 10649600);     // 1,048,576 (2M shorts)
  short*  wout_bf = (short*)(ws + 11698176);     //   262,144
  float2* csum    = (float2*)(ws + 11960320);    // 1,048,576 (512K float2)
  float*  Ssum    = ws + 13008896;               // 2,097,152
  short*  x_bf    = (short*)(ws + 11960320);     //   [alias, see map]
  short*  win_bf  = (short*)(ws + 12484608);     //   [alias]
  short*  xc_bf   = (short*)(ws + 13008896);     //   [alias]
  short*  wx_bf   = (short*)(ws + 14057472);     //   [alias]
  float*  wdtT    = ws + 14344192;               //   [alias]
  float2* AA      = (float2*)(ws + 15106048);    //   256 floats, durable

  // 0) conversions + W_dt transpose + AA table (one kernel)
  cvt_all_k<<<dim3(3249), dim3(256), 0, stream>>>(x, W_in, W_x, W_out, W_dt,
                                                  A_log, A_imag,
                                                  x_bf, win_bf, wx_bf, wout_bf,
                                                  wdtT, AA);
  // 1) xz = x @ W_in^T        (M=2048, N=2048, K=512)
  gemm_bf16_128<<<dim3(16, 16), dim3(256), 0, stream>>>(x_bf, win_bf, xz, 2048, 512);
  // 2) dx.y = silu(dwconv(x_proj)) (+ bf16 copy); in-place silu on z half
  conv_silu_k<<<dim3(8192), dim3(256), 0, stream>>>(xz, conv_w, conv_b,
                                                    (float*)dx, xc_bf);
  // 3) proj = xc @ W_x^T      (M=2048, N=560, K=1024)
  gemm_bf16_64<<<dim3(9, 32), dim3(256), 0, stream>>>(xc_bf, wx_bf, proj, 560, 1024);
  // 4) dx.x = delta; scanin/gates pack
  pack2_k<<<dim3(9216), dim3(256), 0, stream>>>(proj, wdtT, b_dt, (float*)dx,
                                                scanin, gates);
  // 5) split-carry scan
  scan_part1_k<<<dim3(1024), dim3(256), 0, stream>>>(xz, dx, scanin, gates,
                                                     A_log, A_imag, D_param,
                                                     Ssum, csum);
  scan_part2_k<<<dim3(128), dim3(256), 0, stream>>>(Ssum, A_log, A_imag, csum);
  scan_part3_k<<<dim3(8192), dim3(256), 0, stream>>>(xz, xz, Ssum, scanin,
                                                     AA, csum, yg_bf);
  // 6) out = yg_bf @ W_out^T  (M=2048, N=512, K=1024)
  gemm_bf16_64<<<dim3(8, 32), dim3(256), 0, stream>>>(yg_bf, wout_bf, out, 512, 1024);
}

// Round 17
// 172.256 us; speedup vs baseline: 1.0676x; 1.0676x over previous
//
#include <hip/hip_runtime.h>
#include <hip/hip_bf16.h>
#include <math.h>

// Problem constants (B=2, L=1024, d_model=512, d_inner=1024, H=8, N=16, hd=128,
// dt_rank=32, out_dim=560). T = B*L = 2048 tokens.
//
// Pipeline (GEMMs in bf16 MFMA, scan math f32):
//  0) cvt_all: x,W_in,W_x,W_out -> bf16 + W_dt transpose + AA table
//  1) gemm_bf16_128: xz[T,2048] = x_bf @ Win_bf^T        (f32 out)
//  2) conv_silu: dx[t,c].y = silu(dwconv(xz[:,:1024])), xc_bf (bf16 copy),
//     in-place silu on the z-half: xz[t,1024+c] = silu(xz[t,1024+c])
//  3) gemm_bf16_64: proj[T,560] = xc_bf @ Wx_bf^T
//  4) pack2: dx[t,c].x = softplus(proj[:, :32] . W_dtT + b_dt);
//            scanin[t,h,n]={Br,Bi,Cr,Ci}; gates[t,h]={1-lg, lg*eg}
//  5) split-carry chunked scan (chunk=64):
//     part1 (heavy, ONCE): zero-carry scan, 2 channels (n,n+8)/thread
//        (ILP-2, proven R13); shfl_xor 1,2,4 y-reduce.  Stores yd (into xz
//        x-half), S=cum delta sum, csum={h_end}.
//     part2: carry scan over chunks; writes hstart TRANSPOSED into hstT
//        [b,ck,h,n,d] (csum stays read-only).  R15 lesson: [.,d,n] layout
//        made part3's hc loads a 128B-stride scatter -> latency collapse.
//     part3: one thread per output (t,c); inner n-loop (full unroll).
//        hc loads now coalesced via hstT (lane=d contiguous).
//        corr = sum_n mag*(co*u+sn*v); out = (yd+corr)*gz -> yg_bf.
//  6) gemm_bf16_64: out[T,512] = yg_bf @ Wout_bf^T

typedef __attribute__((ext_vector_type(8))) short bf16x8;
typedef __attribute__((ext_vector_type(4))) float f32x4;

#if __has_builtin(__builtin_amdgcn_exp2f)
__device__ __forceinline__ float fexp2(float x) { return __builtin_amdgcn_exp2f(x); }
#else
__device__ __forceinline__ float fexp2(float x) {
  float r; asm("v_exp_f32 %0, %1\n\ts_nop 1" : "=v"(r) : "v"(x)); return r;
}
#endif
#if __has_builtin(__builtin_amdgcn_sinf)
__device__ __forceinline__ float fsin_rev(float x) { return __builtin_amdgcn_sinf(x); }
#else
__device__ __forceinline__ float fsin_rev(float x) {
  float r; asm("v_sin_f32 %0, %1\n\ts_nop 1" : "=v"(r) : "v"(x)); return r;
}
#endif
#if __has_builtin(__builtin_amdgcn_cosf)
__device__ __forceinline__ float fcos_rev(float x) { return __builtin_amdgcn_cosf(x); }
#else
__device__ __forceinline__ float fcos_rev(float x) {
  float r; asm("v_cos_f32 %0, %1\n\ts_nop 1" : "=v"(r) : "v"(x)); return r;
}
#endif

__device__ __forceinline__ short f2bf(float f) {  // round-to-nearest-even
  unsigned u = __float_as_uint(f);
  return (short)((u + 0x7FFFu + ((u >> 16) & 1u)) >> 16);
}

// ---------------------------------------------------------------------------
// Fused f32->bf16 conversion of x, W_in, W_x, W_out (float4 granules) plus
// W_dt transpose plus AA table.  Grid 3249*256 = 831744 (guarded).
// ---------------------------------------------------------------------------
__global__ __launch_bounds__(256)
void cvt_all_k(const float* __restrict__ x, const float* __restrict__ W_in,
               const float* __restrict__ W_x, const float* __restrict__ W_out,
               const float* __restrict__ W_dt, const float* __restrict__ A_log,
               const float* __restrict__ A_imag,
               short* __restrict__ x_bf, short* __restrict__ win_bf,
               short* __restrict__ wx_bf, short* __restrict__ wout_bf,
               float* __restrict__ W_dtT, float2* __restrict__ AA) {
  const int i = blockIdx.x * 256 + threadIdx.x;
  if (i < 798720) {
    const float4* src; short4* dst; int off;
    if (i < 262144)      { src = (const float4*)x;     dst = (short4*)x_bf;    off = i; }
    else if (i < 524288) { src = (const float4*)W_in;  dst = (short4*)win_bf;  off = i - 262144; }
    else if (i < 667648) { src = (const float4*)W_x;   dst = (short4*)wx_bf;   off = i - 524288; }
    else                 { src = (const float4*)W_out; dst = (short4*)wout_bf; off = i - 667648; }
    const float4 v = src[off];
    short4 o;
    o.x = f2bf(v.x); o.y = f2bf(v.y); o.z = f2bf(v.z); o.w = f2bf(v.w);
    dst[off] = o;
  } else if (i < 831488) {
    const int j = i - 798720;  // 0..32767: W_dtT[r*1024+c] = W_dt[c*32+r]
    W_dtT[j] = W_dt[(j & 1023) * 32 + (j >> 10)];
  } else if (i < 831616) {
    const int j = i - 831488;  // 0..127: per-(h,n) scan constants
    AA[j] = make_float2(-__expf(A_log[j]) * 1.44269504f,
                        A_imag[j] * 0.15915494f);
  }
}

// ---------------------------------------------------------------------------
// bf16 MFMA GEMM (NT), 128x128 tile / 256 threads (4 waves x 64x64 quadrant).
// ---------------------------------------------------------------------------
__global__ __launch_bounds__(256)
void gemm_bf16_128(const short* __restrict__ A, const short* __restrict__ W,
                   float* __restrict__ C, int N, int K) {
  __shared__ short As[128][40];
  __shared__ short Ws[128][40];
  const int tid  = threadIdx.x;
  const int m0   = blockIdx.y * 128;
  const int n0   = blockIdx.x * 128;
  const int lane = tid & 63;
  const int wid  = tid >> 6;
  const int wm   = (wid >> 1) * 64;
  const int wn   = (wid & 1) * 64;
  const int r0   = tid >> 2;
  const int q    = (tid & 3) * 8;
  const int lrow = lane & 15;
  const int lk   = (lane >> 4) * 8;

  f32x4 acc[4][4] = {};

  for (int k0 = 0; k0 < K; k0 += 32) {
    const size_t abase = (size_t)(m0 + r0) * K + k0 + q;
    const uint4 a0v = *reinterpret_cast<const uint4*>(A + abase);
    const uint4 a1v = *reinterpret_cast<const uint4*>(A + abase + (size_t)64 * K);
    const int wr0 = n0 + r0, wr1 = wr0 + 64;
    uint4 w0v = make_uint4(0, 0, 0, 0), w1v = make_uint4(0, 0, 0, 0);
    if (wr0 < N) w0v = *reinterpret_cast<const uint4*>(W + (size_t)wr0 * K + k0 + q);
    if (wr1 < N) w1v = *reinterpret_cast<const uint4*>(W + (size_t)wr1 * K + k0 + q);

    __syncthreads();
    *reinterpret_cast<uint4*>(&As[r0][q])      = a0v;
    *reinterpret_cast<uint4*>(&As[r0 + 64][q]) = a1v;
    *reinterpret_cast<uint4*>(&Ws[r0][q])      = w0v;
    *reinterpret_cast<uint4*>(&Ws[r0 + 64][q]) = w1v;
    __syncthreads();

    bf16x8 af[4], bfr[4];
#pragma unroll
    for (int i = 0; i < 4; ++i)
      af[i] = *reinterpret_cast<const bf16x8*>(&As[wm + i * 16 + lrow][lk]);
#pragma unroll
    for (int j = 0; j < 4; ++j)
      bfr[j] = *reinterpret_cast<const bf16x8*>(&Ws[wn + j * 16 + lrow][lk]);
#pragma unroll
    for (int i = 0; i < 4; ++i)
#pragma unroll
      for (int j = 0; j < 4; ++j)
        acc[i][j] = __builtin_amdgcn_mfma_f32_16x16x32_bf16(af[i], bfr[j],
                                                            acc[i][j], 0, 0, 0);
  }

  const int crow = (lane >> 4) * 4;
  const int ccol = lane & 15;
#pragma unroll
  for (int i = 0; i < 4; ++i) {
#pragma unroll
    for (int j = 0; j < 4; ++j) {
      const int col = n0 + wn + j * 16 + ccol;
      if (col < N) {
        const int row = m0 + wm + i * 16 + crow;
#pragma unroll
        for (int r = 0; r < 4; ++r)
          C[(size_t)(row + r) * N + col] = acc[i][j][r];
      }
    }
  }
}

// ---------------------------------------------------------------------------
// bf16 MFMA GEMM (NT), 64x64 tile / 256 threads (4 waves x 32x32 quadrant).
// ---------------------------------------------------------------------------
__global__ __launch_bounds__(256)
void gemm_bf16_64(const short* __restrict__ A, const short* __restrict__ W,
                  float* __restrict__ C, int N, int K) {
  __shared__ short As[64][40];
  __shared__ short Ws[64][40];
  const int tid  = threadIdx.x;
  const int m0   = blockIdx.y * 64;
  const int n0   = blockIdx.x * 64;
  const int lane = tid & 63;
  const int wid  = tid >> 6;
  const int wm   = (wid >> 1) * 32;
  const int wn   = (wid & 1) * 32;
  const int r0   = tid >> 2;
  const int q    = (tid & 3) * 8;
  const int lrow = lane & 15;
  const int lk   = (lane >> 4) * 8;

  f32x4 acc[2][2] = {};

  for (int k0 = 0; k0 < K; k0 += 32) {
    const uint4 a0v =
        *reinterpret_cast<const uint4*>(A + (size_t)(m0 + r0) * K + k0 + q);
    const int wr0 = n0 + r0;
    uint4 w0v = make_uint4(0, 0, 0, 0);
    if (wr0 < N) w0v = *reinterpret_cast<const uint4*>(W + (size_t)wr0 * K + k0 + q);

    __syncthreads();
    *reinterpret_cast<uint4*>(&As[r0][q]) = a0v;
    *reinterpret_cast<uint4*>(&Ws[r0][q]) = w0v;
    __syncthreads();

    bf16x8 af[2], bfr[2];
#pragma unroll
    for (int i = 0; i < 2; ++i)
      af[i] = *reinterpret_cast<const bf16x8*>(&As[wm + i * 16 + lrow][lk]);
#pragma unroll
    for (int j = 0; j < 2; ++j)
      bfr[j] = *reinterpret_cast<const bf16x8*>(&Ws[wn + j * 16 + lrow][lk]);
#pragma unroll
    for (int i = 0; i < 2; ++i)
#pragma unroll
      for (int j = 0; j < 2; ++j)
        acc[i][j] = __builtin_amdgcn_mfma_f32_16x16x32_bf16(af[i], bfr[j],
                                                            acc[i][j], 0, 0, 0);
  }

  const int crow = (lane >> 4) * 4;
  const int ccol = lane & 15;
#pragma unroll
  for (int i = 0; i < 2; ++i) {
#pragma unroll
    for (int j = 0; j < 2; ++j) {
      const int col = n0 + wn + j * 16 + ccol;
      if (col < N) {
        const int row = m0 + wm + i * 16 + crow;
#pragma unroll
        for (int r = 0; r < 4; ++r)
          C[(size_t)(row + r) * N + col] = acc[i][j][r];
      }
    }
  }
}

// ---------------------------------------------------------------------------
// Causal depthwise conv (K=3) + silu; writes dx.y (f32) and xc_bf (bf16).
// Also applies silu IN-PLACE to the z half: xz[t,1024+c] = silu(...).
// ---------------------------------------------------------------------------
__global__ __launch_bounds__(256)
void conv_silu_k(float* __restrict__ xz, const float* __restrict__ conv_w,
                 const float* __restrict__ conv_b, float* __restrict__ dxf,
                 short* __restrict__ xcb) {
  const int idx = blockIdx.x * 256 + threadIdx.x;
  const int c = idx & 1023;
  const int t = idx >> 10;
  const int l = t & 1023;
  const float* xp = xz + (size_t)t * 2048 + c;
  float acc = conv_b[c];
  const float w0 = conv_w[c * 3 + 0];
  const float w1 = conv_w[c * 3 + 1];
  const float w2 = conv_w[c * 3 + 2];
  acc += w2 * xp[0];
  if (l >= 1) acc += w1 * xp[-2048];
  if (l >= 2) acc += w0 * xp[-2 * 2048];
  const float v = acc / (1.f + __expf(-acc));
  dxf[2 * (size_t)idx + 1] = v;
  xcb[idx] = f2bf(v);
  // in-place silu on z
  float* zp = xz + (size_t)t * 2048 + 1024 + c;
  const float zv = *zp;
  *zp = zv / (1.f + __expf(-zv));
}

// ---------------------------------------------------------------------------
// pack2: fused delta + scanin-pack + gates.
// ---------------------------------------------------------------------------
__global__ __launch_bounds__(256)
void pack2_k(const float* __restrict__ proj, const float* __restrict__ W_dtT,
             const float* __restrict__ b_dt, float* __restrict__ dxf,
             float4* __restrict__ scanin, float2* __restrict__ gates) {
  const int idx = blockIdx.x * 256 + threadIdx.x;  // 2097152 + 262144
  if (idx < 2097152) {
    const int c = idx & 1023;
    const int t = idx >> 10;
    const float* pr = proj + (size_t)t * 560;
    float acc = b_dt[c];
#pragma unroll
    for (int r = 0; r < 32; ++r) acc = fmaf(pr[r], W_dtT[r * 1024 + c], acc);
    dxf[2 * (size_t)idx] = fmaxf(acc, 0.f) + log1pf(__expf(-fabsf(acc)));
  } else {
    const int j = idx - 2097152;
    const int n = j & 15;
    const int h = (j >> 4) & 7;
    const int t = j >> 7;
    const float* pr = proj + (size_t)t * 560;
    const int hn = h * 16 + n;
    scanin[j] = make_float4(pr[32 + hn], pr[160 + hn], pr[288 + hn], pr[416 + hn]);
    if (n == 0) {
      const float lg = 1.f / (1.f + __expf(-pr[544 + h]));
      const float eg = 1.f / (1.f + __expf(-pr[552 + h]));
      gates[t * 8 + h] = make_float2(1.f - lg, lg * eg);
    }
  }
}

// ---------------------------------------------------------------------------
// Split-carry chunked scan, part1 with 2 channels (n, n+8) per thread.
// gid bits: [b:1][ck:4][h:3][d:7][n:3] -> 262144 threads (1024 blocks).
// y-reduce: __shfl_xor 1,2,4 butterfly (direction-free, group-closed).
// ---------------------------------------------------------------------------
__global__ __launch_bounds__(256)
void scan_part1_k(float* __restrict__ pyd,        // xz base (x-half, yd out)
                  const float2* __restrict__ dx,
                  const float4* __restrict__ scanin,
                  const float2* __restrict__ gates,
                  const float* __restrict__ A_log, const float* __restrict__ A_imag,
                  const float* __restrict__ D_param,
                  float* __restrict__ Ssum, float2* __restrict__ csum) {
  const int gid = blockIdx.x * 256 + threadIdx.x;  // 262144 total
  const int n  = gid & 7;            // this thread handles n and n+8
  const int d  = (gid >> 3) & 127;
  const int h  = (gid >> 10) & 7;
  const int ck = (gid >> 13) & 15;
  const int b  = gid >> 17;
  const int c  = h * 128 + d;

  const float Are2a = -__expf(A_log[h * 16 + n])     * 1.44269504f;
  const float AimRa =  A_imag[h * 16 + n]            * 0.15915494f;
  const float Are2b = -__expf(A_log[h * 16 + n + 8]) * 1.44269504f;
  const float AimRb =  A_imag[h * 16 + n + 8]        * 0.15915494f;
  const float Dc   = D_param[c];
  const int t0 = b * 1024 + ck * 64;

  float bxpra = 0.f, bxpia = 0.f, bxprb = 0.f, bxpib = 0.f;
  if (ck > 0) {
    const float xv = dx[(size_t)(t0 - 1) * 1024 + c].y;
    const float2 bpa =
        *reinterpret_cast<const float2*>(&scanin[(size_t)(t0 - 1) * 128 + h * 16 + n]);
    const float2 bpb =
        *reinterpret_cast<const float2*>(&scanin[(size_t)(t0 - 1) * 128 + h * 16 + n + 8]);
    bxpra = xv * bpa.x; bxpia = xv * bpa.y;
    bxprb = xv * bpb.x; bxpib = xv * bpb.y;
  }

  // 32-bit byte offsets from uniform bases
  unsigned odx = ((unsigned)t0 * 1024u + (unsigned)c) * 8u;
  unsigned osc = ((unsigned)t0 * 128u + (unsigned)(h * 16 + n)) * 16u;  // +128B for n+8
  unsigned ogt = ((unsigned)t0 * 8u + (unsigned)h) * 8u;
  unsigned opy = ((unsigned)t0 * 2048u + (unsigned)c) * 4u;
  unsigned oss = ((unsigned)t0 * 1024u + (unsigned)c) * 4u;

  float S = 0.f;
  float hra = 0.f, hia = 0.f, hrb = 0.f, hib = 0.f;
#pragma unroll 4
  for (int l = 0; l < 64; ++l) {
    const float2 dxv = *(const float2*)((const char*)dx + odx);
    const float4 bca = *(const float4*)((const char*)scanin + osc);
    const float4 bcb = *(const float4*)((const char*)scanin + osc + 128u);
    const float2 bg  = *(const float2*)((const char*)gates + ogt);

    const float dv = dxv.x, xv = dxv.y;
    const float betas = dv * bg.x;
    const float gam   = dv * bg.y;
    S += dv;

    // channel A (state index n)
    {
      const float mag = fexp2(dv * Are2a);
      const float rev = dv * AimRa;
      const float sn = fsin_rev(rev), co = fcos_rev(rev);
      const float are = mag * co, aim = mag * sn;
      const float bxr = xv * bca.x, bxi = xv * bca.y;
      const float tr = fmaf(betas, bxpra, hra);
      const float ti = fmaf(betas, bxpia, hia);
      hra = fmaf(are, tr, fmaf(-aim, ti, gam * bxr));
      hia = fmaf(are, ti, fmaf(aim, tr, gam * bxi));
      bxpra = bxr; bxpia = bxi;
    }
    // channel B (state index n+8)
    {
      const float mag = fexp2(dv * Are2b);
      const float rev = dv * AimRb;
      const float sn = fsin_rev(rev), co = fcos_rev(rev);
      const float are = mag * co, aim = mag * sn;
      const float bxr = xv * bcb.x, bxi = xv * bcb.y;
      const float tr = fmaf(betas, bxprb, hrb);
      const float ti = fmaf(betas, bxpib, hib);
      hrb = fmaf(are, tr, fmaf(-aim, ti, gam * bxr));
      hib = fmaf(are, ti, fmaf(aim, tr, gam * bxi));
      bxprb = bxr; bxpib = bxi;
    }

    float y = fmaf(hra, bca.z, hia * bca.w) + fmaf(hrb, bcb.z, hib * bcb.w);
    y += __shfl_xor(y, 1);   // butterfly: direction-free, stays in 8-group
    y += __shfl_xor(y, 2);
    y += __shfl_xor(y, 4);

    if (n == 0) {
      *(float*)((char*)pyd + opy)  = fmaf(Dc, xv, y);  // yd (ungated)
      *(float*)((char*)Ssum + oss) = S;
    }
    odx += 8192u; osc += 2048u; ogt += 64u; opy += 8192u; oss += 4096u;
  }
  const int sbase = (((b * 16 + ck) * 8 + h) << 11) + d * 16 + n;
  csum[sbase]     = make_float2(hra, hia);
  csum[sbase + 8] = make_float2(hrb, hib);
}

// ---------------------------------------------------------------------------
// part2: carry scan over 16 chunk summaries; A_chunk from S64 (shared-A
// cumulative-product identity).  Reads csum [.,d,n]; writes hstT TRANSPOSED
// [b,ck,h,n,d] so part3's per-n loads are lane-coalesced (R15 fix).
// ---------------------------------------------------------------------------
__global__ __launch_bounds__(256)
void scan_part2_k(const float* __restrict__ Ssum, const float* __restrict__ A_log,
                  const float* __restrict__ A_imag, const float2* __restrict__ csum,
                  float2* __restrict__ hstT) {
  const int gid = blockIdx.x * 256 + threadIdx.x;  // 32768 total
  const int low = gid & 2047;                      // d*16+n
  const int h   = (gid >> 11) & 7;
  const int b   = gid >> 14;
  const int n   = low & 15;
  const int dd  = low >> 4;
  const int c   = h * 128 + dd;
  const float Are2 = -__expf(A_log[h * 16 + n]) * 1.44269504f;
  const float AimR = A_imag[h * 16 + n] * 0.15915494f;
  float hr = 0.f, hi = 0.f;  // carry
#pragma unroll
  for (int ck = 0; ck < 16; ++ck) {
    const int base = ((b * 16 + ck) * 8 + h) << 11;
    const float2 he = csum[base + low];
    const float S64 = Ssum[(size_t)(b * 1024 + ck * 64 + 63) * 1024 + c];
    hstT[base + n * 128 + dd] = make_float2(hr, hi);  // transposed hstart
    const float mag = fexp2(S64 * Are2);
    const float rev = S64 * AimR;
    const float sn = fsin_rev(rev), co = fcos_rev(rev);
    const float ar = mag * co, ai = mag * sn;
    const float nhr = fmaf(ar, hr, fmaf(-ai, hi, he.x));
    const float nhi = fmaf(ar, hi, fmaf(ai, hr, he.y));
    hr = nhr; hi = nhi;
  }
}

// ---------------------------------------------------------------------------
// part3: one thread per output (t,c); inner n-loop over 16 states (full
// unroll; all loads independent and coalesced/broadcast).
//   corr = sum_n mag_n*(co_n*u_n + sn_n*v_n),  u=Cr*hcr+Ci*hci,
//   v=Ci*hcr-Cr*hci;  out[t,c] = (yd + corr) * gz.
// hc from hstT [b,ck,h,n,d]: lane c -> consecutive d -> one 512B
// transaction per n (R15's [.,d,n] layout was a 128B-stride scatter).
// ---------------------------------------------------------------------------
__global__ __launch_bounds__(256)
void scan_part3_k(const float* __restrict__ gz, const float* __restrict__ pyd,
                  const float* __restrict__ Ssum, const float4* __restrict__ scanin,
                  const float2* __restrict__ AA, const float2* __restrict__ hstT,
                  short* __restrict__ ygb) {
  const int gid = blockIdx.x * 256 + threadIdx.x;  // 2,097,152
  const int c  = gid & 1023;
  const int t  = gid >> 10;
  const int h  = c >> 7;
  const int d  = c & 127;
  const int b  = t >> 10;
  const int ck = (t >> 6) & 15;

  const float S   = Ssum[(size_t)t * 1024 + c];
  const float ydv = pyd[(size_t)t * 2048 + c];
  const float gzv = gz[(size_t)t * 2048 + 1024 + c];

  const float2* hc = hstT + ((((b * 16 + ck) * 8 + h) << 11) + d);  // + n*128
  const float2* cv = reinterpret_cast<const float2*>(scanin + (size_t)t * 128 + h * 16);
  const float2* aa = AA + h * 16;

  float corr = 0.f;
#pragma unroll
  for (int n = 0; n < 16; ++n) {
    const float2 a   = aa[n];
    const float2 hcv = hc[n * 128];       // coalesced: lanes = consecutive d
    const float2 cvv = cv[2 * n + 1];     // {Cr, Ci}, wave-broadcast
    const float mag = fexp2(S * a.x);
    const float rev = S * a.y;
    const float sn = fsin_rev(rev), co = fcos_rev(rev);
    const float u = fmaf(cvv.x, hcv.x, cvv.y * hcv.y);
    const float v = fmaf(cvv.y, hcv.x, -cvv.x * hcv.y);
    corr = fmaf(mag, fmaf(co, u, sn * v), corr);
  }
  ygb[(size_t)t * 1024 + c] = f2bf((ydv + corr) * gzv);
}

// ---------------------------------------------------------------------------
extern "C" void kernel_launch(void* const* d_in, const int* in_sizes, int n_in,
                              void* d_out, int out_size, void* d_ws, size_t ws_size,
                              hipStream_t stream) {
  (void)in_sizes; (void)n_in; (void)out_size; (void)ws_size;
  const float* x       = (const float*)d_in[0];
  const float* W_in    = (const float*)d_in[1];
  const float* conv_w  = (const float*)d_in[2];
  const float* conv_b  = (const float*)d_in[3];
  const float* W_x     = (const float*)d_in[4];
  const float* W_dt    = (const float*)d_in[5];
  const float* b_dt    = (const float*)d_in[6];
  const float* A_log   = (const float*)d_in[7];
  const float* A_imag  = (const float*)d_in[8];
  const float* D_param = (const float*)d_in[9];
  const float* W_out   = (const float*)d_in[10];
  float* out = (float*)d_out;

  // workspace layout (float offsets); total 16,154,880 floats = 61.6 MiB.
  // xz x-half (cols 0-1023) is dead after conv_silu -> part1 stores yd there.
  // csum stays read-only in part2; hstT is the transposed carry table.
  // Aliases live inside csum+Ssum's slot [11960320, 15106048); all are dead
  // before part1 writes csum/Ssum.  AA and hstT live past the scan -> own slots.
  //   x_bf   [11960320, 12484608)   1,048,576 shorts
  //   win_bf [12484608, 13008896)   1,048,576 shorts
  //   xc_bf  [13008896, 14057472)   2,097,152 shorts
  //   wx_bf  [14057472, 14344192)     573,440 shorts
  //   wdtT   [14344192, 14376960)      32,768 floats
  //   AA     [15106048, 15106304)     128 float2 (not aliased)
  //   hstT   [15106304, 16154880)     512K float2 (not aliased)
  float* ws = (float*)d_ws;
  float*  xz      = ws;                          // 4,194,304 (yd aliases x-half)
  float*  proj    = ws + 4194304;                // 1,146,880
  float2* dx      = (float2*)(ws + 5341184);     // 4,194,304 (2M float2)
  float4* scanin  = (float4*)(ws + 9535488);     // 1,048,576
  float2* gates   = (float2*)(ws + 10584064);    //    65,536
  short*  yg_bf   = (short*)(ws + 10649600);     // 1,048,576 (2M shorts)
  short*  wout_bf = (short*)(ws + 11698176);     //   262,144
  float2* csum    = (float2*)(ws + 11960320);    // 1,048,576 (512K float2)
  float*  Ssum    = ws + 13008896;               // 2,097,152
  short*  x_bf    = (short*)(ws + 11960320);     //   [alias, see map]
  short*  win_bf  = (short*)(ws + 12484608);     //   [alias]
  short*  xc_bf   = (short*)(ws + 13008896);     //   [alias]
  short*  wx_bf   = (short*)(ws + 14057472);     //   [alias]
  float*  wdtT    = ws + 14344192;               //   [alias]
  float2* AA      = (float2*)(ws + 15106048);    //   durable
  float2* hstT    = (float2*)(ws + 15106304);    //   durable (4 MB)

  // 0) conversions + W_dt transpose + AA table (one kernel)
  cvt_all_k<<<dim3(3249), dim3(256), 0, stream>>>(x, W_in, W_x, W_out, W_dt,
                                                  A_log, A_imag,
                                                  x_bf, win_bf, wx_bf, wout_bf,
                                                  wdtT, AA);
  // 1) xz = x @ W_in^T        (M=2048, N=2048, K=512)
  gemm_bf16_128<<<dim3(16, 16), dim3(256), 0, stream>>>(x_bf, win_bf, xz, 2048, 512);
  // 2) dx.y = silu(dwconv(x_proj)) (+ bf16 copy); in-place silu on z half
  conv_silu_k<<<dim3(8192), dim3(256), 0, stream>>>(xz, conv_w, conv_b,
                                                    (float*)dx, xc_bf);
  // 3) proj = xc @ W_x^T      (M=2048, N=560, K=1024)
  gemm_bf16_64<<<dim3(9, 32), dim3(256), 0, stream>>>(xc_bf, wx_bf, proj, 560, 1024);
  // 4) dx.x = delta; scanin/gates pack
  pack2_k<<<dim3(9216), dim3(256), 0, stream>>>(proj, wdtT, b_dt, (float*)dx,
                                                scanin, gates);
  // 5) split-carry scan
  scan_part1_k<<<dim3(1024), dim3(256), 0, stream>>>(xz, dx, scanin, gates,
                                                     A_log, A_imag, D_param,
                                                     Ssum, csum);
  scan_part2_k<<<dim3(128), dim3(256), 0, stream>>>(Ssum, A_log, A_imag, csum,
                                                    hstT);
  scan_part3_k<<<dim3(8192), dim3(256), 0, stream>>>(xz, xz, Ssum, scanin,
                                                     AA, hstT, yg_bf);
  // 6) out = yg_bf @ W_out^T  (M=2048, N=512, K=1024)
  gemm_bf16_64<<<dim3(8, 32), dim3(256), 0, stream>>>(yg_bf, wout_bf, out, 512, 1024);
}

// Round 18
// 170.415 us; speedup vs baseline: 1.0791x; 1.0108x over previous
//
#include <hip/hip_runtime.h>
#include <hip/hip_bf16.h>
#include <math.h>

// Problem constants (B=2, L=1024, d_model=512, d_inner=1024, H=8, N=16, hd=128,
// dt_rank=32, out_dim=560). T = B*L = 2048 tokens.
//
// Pipeline (GEMMs in bf16 MFMA, scan math f32):
//  0) cvt_all: x,W_in,W_x,W_out -> bf16 + W_dt transpose + AA table
//  1) gemm_bf16_128: xz[T,2048] = x_bf @ Win_bf^T        (f32 out)
//  2) conv_silu: dx[t,c].y = silu(dwconv(xz[:,:1024])), xc_bf (bf16 copy),
//     in-place silu on the z-half: xz[t,1024+c] = silu(xz[t,1024+c])
//  3) gemm_bf16_64: proj[T,560] = xc_bf @ Wx_bf^T
//  4) pack2: dx[t,c].x = softplus(proj[:, :32] . W_dtT + b_dt);
//            scanin[t,h,n]={Br,Bi,Cr,Ci}; gates[t,h]={1-lg, lg*eg}
//  5) split-carry chunked scan (chunk=64):
//     part1 (heavy, ONCE): zero-carry scan, 2 channels (n,n+8)/thread
//        (ILP-2, proven R13); shfl_xor 1,2,4 y-reduce.  Stores yd (into xz
//        x-half), S=cum delta sum, csum={h_end}.
//     part2: carry scan over chunks; writes hstart TRANSPOSED into hstT
//        [b,ck,h,n,d] (csum stays read-only).  R15 lesson: [.,d,n] layout
//        made part3's hc loads a 128B-stride scatter -> latency collapse.
//     part3: one thread per output (t,c); inner n-loop (full unroll).
//        hc loads now coalesced via hstT (lane=d contiguous).
//        corr = sum_n mag*(co*u+sn*v); out = (yd+corr)*gz -> yg_bf.
//  6) gemm_bf16_64: out[T,512] = yg_bf @ Wout_bf^T

typedef __attribute__((ext_vector_type(8))) short bf16x8;
typedef __attribute__((ext_vector_type(4))) float f32x4;

#if __has_builtin(__builtin_amdgcn_exp2f)
__device__ __forceinline__ float fexp2(float x) { return __builtin_amdgcn_exp2f(x); }
#else
__device__ __forceinline__ float fexp2(float x) {
  float r; asm("v_exp_f32 %0, %1\n\ts_nop 1" : "=v"(r) : "v"(x)); return r;
}
#endif
#if __has_builtin(__builtin_amdgcn_sinf)
__device__ __forceinline__ float fsin_rev(float x) { return __builtin_amdgcn_sinf(x); }
#else
__device__ __forceinline__ float fsin_rev(float x) {
  float r; asm("v_sin_f32 %0, %1\n\ts_nop 1" : "=v"(r) : "v"(x)); return r;
}
#endif
#if __has_builtin(__builtin_amdgcn_cosf)
__device__ __forceinline__ float fcos_rev(float x) { return __builtin_amdgcn_cosf(x); }
#else
__device__ __forceinline__ float fcos_rev(float x) {
  float r; asm("v_cos_f32 %0, %1\n\ts_nop 1" : "=v"(r) : "v"(x)); return r;
}
#endif

__device__ __forceinline__ short f2bf(float f) {  // round-to-nearest-even
  unsigned u = __float_as_uint(f);
  return (short)((u + 0x7FFFu + ((u >> 16) & 1u)) >> 16);
}

// ---------------------------------------------------------------------------
// Fused f32->bf16 conversion of x, W_in, W_x, W_out (float4 granules) plus
// W_dt transpose plus AA table.  Grid 3249*256 = 831744 (guarded).
// ---------------------------------------------------------------------------
__global__ __launch_bounds__(256)
void cvt_all_k(const float* __restrict__ x, const float* __restrict__ W_in,
               const float* __restrict__ W_x, const float* __restrict__ W_out,
               const float* __restrict__ W_dt, const float* __restrict__ A_log,
               const float* __restrict__ A_imag,
               short* __restrict__ x_bf, short* __restrict__ win_bf,
               short* __restrict__ wx_bf, short* __restrict__ wout_bf,
               float* __restrict__ W_dtT, float2* __restrict__ AA) {
  const int i = blockIdx.x * 256 + threadIdx.x;
  if (i < 798720) {
    const float4* src; short4* dst; int off;
    if (i < 262144)      { src = (const float4*)x;     dst = (short4*)x_bf;    off = i; }
    else if (i < 524288) { src = (const float4*)W_in;  dst = (short4*)win_bf;  off = i - 262144; }
    else if (i < 667648) { src = (const float4*)W_x;   dst = (short4*)wx_bf;   off = i - 524288; }
    else                 { src = (const float4*)W_out; dst = (short4*)wout_bf; off = i - 667648; }
    const float4 v = src[off];
    short4 o;
    o.x = f2bf(v.x); o.y = f2bf(v.y); o.z = f2bf(v.z); o.w = f2bf(v.w);
    dst[off] = o;
  } else if (i < 831488) {
    const int j = i - 798720;  // 0..32767: W_dtT[r*1024+c] = W_dt[c*32+r]
    W_dtT[j] = W_dt[(j & 1023) * 32 + (j >> 10)];
  } else if (i < 831616) {
    const int j = i - 831488;  // 0..127: per-(h,n) scan constants
    AA[j] = make_float2(-__expf(A_log[j]) * 1.44269504f,
                        A_imag[j] * 0.15915494f);
  }
}

// ---------------------------------------------------------------------------
// bf16 MFMA GEMM (NT), 128x128 tile / 256 threads (4 waves x 64x64 quadrant).
// ---------------------------------------------------------------------------
__global__ __launch_bounds__(256)
void gemm_bf16_128(const short* __restrict__ A, const short* __restrict__ W,
                   float* __restrict__ C, int N, int K) {
  __shared__ short As[128][40];
  __shared__ short Ws[128][40];
  const int tid  = threadIdx.x;
  const int m0   = blockIdx.y * 128;
  const int n0   = blockIdx.x * 128;
  const int lane = tid & 63;
  const int wid  = tid >> 6;
  const int wm   = (wid >> 1) * 64;
  const int wn   = (wid & 1) * 64;
  const int r0   = tid >> 2;
  const int q    = (tid & 3) * 8;
  const int lrow = lane & 15;
  const int lk   = (lane >> 4) * 8;

  f32x4 acc[4][4] = {};

  for (int k0 = 0; k0 < K; k0 += 32) {
    const size_t abase = (size_t)(m0 + r0) * K + k0 + q;
    const uint4 a0v = *reinterpret_cast<const uint4*>(A + abase);
    const uint4 a1v = *reinterpret_cast<const uint4*>(A + abase + (size_t)64 * K);
    const int wr0 = n0 + r0, wr1 = wr0 + 64;
    uint4 w0v = make_uint4(0, 0, 0, 0), w1v = make_uint4(0, 0, 0, 0);
    if (wr0 < N) w0v = *reinterpret_cast<const uint4*>(W + (size_t)wr0 * K + k0 + q);
    if (wr1 < N) w1v = *reinterpret_cast<const uint4*>(W + (size_t)wr1 * K + k0 + q);

    __syncthreads();
    *reinterpret_cast<uint4*>(&As[r0][q])      = a0v;
    *reinterpret_cast<uint4*>(&As[r0 + 64][q]) = a1v;
    *reinterpret_cast<uint4*>(&Ws[r0][q])      = w0v;
    *reinterpret_cast<uint4*>(&Ws[r0 + 64][q]) = w1v;
    __syncthreads();

    bf16x8 af[4], bfr[4];
#pragma unroll
    for (int i = 0; i < 4; ++i)
      af[i] = *reinterpret_cast<const bf16x8*>(&As[wm + i * 16 + lrow][lk]);
#pragma unroll
    for (int j = 0; j < 4; ++j)
      bfr[j] = *reinterpret_cast<const bf16x8*>(&Ws[wn + j * 16 + lrow][lk]);
#pragma unroll
    for (int i = 0; i < 4; ++i)
#pragma unroll
      for (int j = 0; j < 4; ++j)
        acc[i][j] = __builtin_amdgcn_mfma_f32_16x16x32_bf16(af[i], bfr[j],
                                                            acc[i][j], 0, 0, 0);
  }

  const int crow = (lane >> 4) * 4;
  const int ccol = lane & 15;
#pragma unroll
  for (int i = 0; i < 4; ++i) {
#pragma unroll
    for (int j = 0; j < 4; ++j) {
      const int col = n0 + wn + j * 16 + ccol;
      if (col < N) {
        const int row = m0 + wm + i * 16 + crow;
#pragma unroll
        for (int r = 0; r < 4; ++r)
          C[(size_t)(row + r) * N + col] = acc[i][j][r];
      }
    }
  }
}

// ---------------------------------------------------------------------------
// bf16 MFMA GEMM (NT), 64x64 tile / 256 threads (4 waves x 32x32 quadrant).
// ---------------------------------------------------------------------------
__global__ __launch_bounds__(256)
void gemm_bf16_64(const short* __restrict__ A, const short* __restrict__ W,
                  float* __restrict__ C, int N, int K) {
  __shared__ short As[64][40];
  __shared__ short Ws[64][40];
  const int tid  = threadIdx.x;
  const int m0   = blockIdx.y * 64;
  const int n0   = blockIdx.x * 64;
  const int lane = tid & 63;
  const int wid  = tid >> 6;
  const int wm   = (wid >> 1) * 32;
  const int wn   = (wid & 1) * 32;
  const int r0   = tid >> 2;
  const int q    = (tid & 3) * 8;
  const int lrow = lane & 15;
  const int lk   = (lane >> 4) * 8;

  f32x4 acc[2][2] = {};

  for (int k0 = 0; k0 < K; k0 += 32) {
    const uint4 a0v =
        *reinterpret_cast<const uint4*>(A + (size_t)(m0 + r0) * K + k0 + q);
    const int wr0 = n0 + r0;
    uint4 w0v = make_uint4(0, 0, 0, 0);
    if (wr0 < N) w0v = *reinterpret_cast<const uint4*>(W + (size_t)wr0 * K + k0 + q);

    __syncthreads();
    *reinterpret_cast<uint4*>(&As[r0][q]) = a0v;
    *reinterpret_cast<uint4*>(&Ws[r0][q]) = w0v;
    __syncthreads();

    bf16x8 af[2], bfr[2];
#pragma unroll
    for (int i = 0; i < 2; ++i)
      af[i] = *reinterpret_cast<const bf16x8*>(&As[wm + i * 16 + lrow][lk]);
#pragma unroll
    for (int j = 0; j < 2; ++j)
      bfr[j] = *reinterpret_cast<const bf16x8*>(&Ws[wn + j * 16 + lrow][lk]);
#pragma unroll
    for (int i = 0; i < 2; ++i)
#pragma unroll
      for (int j = 0; j < 2; ++j)
        acc[i][j] = __builtin_amdgcn_mfma_f32_16x16x32_bf16(af[i], bfr[j],
                                                            acc[i][j], 0, 0, 0);
  }

  const int crow = (lane >> 4) * 4;
  const int ccol = lane & 15;
#pragma unroll
  for (int i = 0; i < 2; ++i) {
#pragma unroll
    for (int j = 0; j < 2; ++j) {
      const int col = n0 + wn + j * 16 + ccol;
      if (col < N) {
        const int row = m0 + wm + i * 16 + crow;
#pragma unroll
        for (int r = 0; r < 4; ++r)
          C[(size_t)(row + r) * N + col] = acc[i][j][r];
      }
    }
  }
}

// ---------------------------------------------------------------------------
// Causal depthwise conv (K=3) + silu; writes dx.y (f32) and xc_bf (bf16).
// Also applies silu IN-PLACE to the z half: xz[t,1024+c] = silu(...).
// ---------------------------------------------------------------------------
__global__ __launch_bounds__(256)
void conv_silu_k(float* __restrict__ xz, const float* __restrict__ conv_w,
                 const float* __restrict__ conv_b, float* __restrict__ dxf,
                 short* __restrict__ xcb) {
  const int idx = blockIdx.x * 256 + threadIdx.x;
  const int c = idx & 1023;
  const int t = idx >> 10;
  const int l = t & 1023;
  const float* xp = xz + (size_t)t * 2048 + c;
  float acc = conv_b[c];
  const float w0 = conv_w[c * 3 + 0];
  const float w1 = conv_w[c * 3 + 1];
  const float w2 = conv_w[c * 3 + 2];
  acc += w2 * xp[0];
  if (l >= 1) acc += w1 * xp[-2048];
  if (l >= 2) acc += w0 * xp[-2 * 2048];
  const float v = acc / (1.f + __expf(-acc));
  dxf[2 * (size_t)idx + 1] = v;
  xcb[idx] = f2bf(v);
  // in-place silu on z
  float* zp = xz + (size_t)t * 2048 + 1024 + c;
  const float zv = *zp;
  *zp = zv / (1.f + __expf(-zv));
}

// ---------------------------------------------------------------------------
// pack2: fused delta + scanin-pack + gates.
// ---------------------------------------------------------------------------
__global__ __launch_bounds__(256)
void pack2_k(const float* __restrict__ proj, const float* __restrict__ W_dtT,
             const float* __restrict__ b_dt, float* __restrict__ dxf,
             float4* __restrict__ scanin, float2* __restrict__ gates) {
  const int idx = blockIdx.x * 256 + threadIdx.x;  // 2097152 + 262144
  if (idx < 2097152) {
    const int c = idx & 1023;
    const int t = idx >> 10;
    const float* pr = proj + (size_t)t * 560;
    float acc = b_dt[c];
#pragma unroll
    for (int r = 0; r < 32; ++r) acc = fmaf(pr[r], W_dtT[r * 1024 + c], acc);
    dxf[2 * (size_t)idx] = fmaxf(acc, 0.f) + log1pf(__expf(-fabsf(acc)));
  } else {
    const int j = idx - 2097152;
    const int n = j & 15;
    const int h = (j >> 4) & 7;
    const int t = j >> 7;
    const float* pr = proj + (size_t)t * 560;
    const int hn = h * 16 + n;
    scanin[j] = make_float4(pr[32 + hn], pr[160 + hn], pr[288 + hn], pr[416 + hn]);
    if (n == 0) {
      const float lg = 1.f / (1.f + __expf(-pr[544 + h]));
      const float eg = 1.f / (1.f + __expf(-pr[552 + h]));
      gates[t * 8 + h] = make_float2(1.f - lg, lg * eg);
    }
  }
}

// ---------------------------------------------------------------------------
// Split-carry chunked scan, part1 with 2 channels (n, n+8) per thread.
// gid bits: [b:1][ck:4][h:3][d:7][n:3] -> 262144 threads (1024 blocks).
// y-reduce: __shfl_xor 1,2,4 butterfly (direction-free, group-closed).
// ---------------------------------------------------------------------------
__global__ __launch_bounds__(256)
void scan_part1_k(float* __restrict__ pyd,        // xz base (x-half, yd out)
                  const float2* __restrict__ dx,
                  const float4* __restrict__ scanin,
                  const float2* __restrict__ gates,
                  const float* __restrict__ A_log, const float* __restrict__ A_imag,
                  const float* __restrict__ D_param,
                  float* __restrict__ Ssum, float2* __restrict__ csum) {
  const int gid = blockIdx.x * 256 + threadIdx.x;  // 262144 total
  const int n  = gid & 7;            // this thread handles n and n+8
  const int d  = (gid >> 3) & 127;
  const int h  = (gid >> 10) & 7;
  const int ck = (gid >> 13) & 15;
  const int b  = gid >> 17;
  const int c  = h * 128 + d;

  const float Are2a = -__expf(A_log[h * 16 + n])     * 1.44269504f;
  const float AimRa =  A_imag[h * 16 + n]            * 0.15915494f;
  const float Are2b = -__expf(A_log[h * 16 + n + 8]) * 1.44269504f;
  const float AimRb =  A_imag[h * 16 + n + 8]        * 0.15915494f;
  const float Dc   = D_param[c];
  const int t0 = b * 1024 + ck * 64;

  float bxpra = 0.f, bxpia = 0.f, bxprb = 0.f, bxpib = 0.f;
  if (ck > 0) {
    const float xv = dx[(size_t)(t0 - 1) * 1024 + c].y;
    const float2 bpa =
        *reinterpret_cast<const float2*>(&scanin[(size_t)(t0 - 1) * 128 + h * 16 + n]);
    const float2 bpb =
        *reinterpret_cast<const float2*>(&scanin[(size_t)(t0 - 1) * 128 + h * 16 + n + 8]);
    bxpra = xv * bpa.x; bxpia = xv * bpa.y;
    bxprb = xv * bpb.x; bxpib = xv * bpb.y;
  }

  // 32-bit byte offsets from uniform bases
  unsigned odx = ((unsigned)t0 * 1024u + (unsigned)c) * 8u;
  unsigned osc = ((unsigned)t0 * 128u + (unsigned)(h * 16 + n)) * 16u;  // +128B for n+8
  unsigned ogt = ((unsigned)t0 * 8u + (unsigned)h) * 8u;
  unsigned opy = ((unsigned)t0 * 2048u + (unsigned)c) * 4u;
  unsigned oss = ((unsigned)t0 * 1024u + (unsigned)c) * 4u;

  float S = 0.f;
  float hra = 0.f, hia = 0.f, hrb = 0.f, hib = 0.f;
#pragma unroll 4
  for (int l = 0; l < 64; ++l) {
    const float2 dxv = *(const float2*)((const char*)dx + odx);
    const float4 bca = *(const float4*)((const char*)scanin + osc);
    const float4 bcb = *(const float4*)((const char*)scanin + osc + 128u);
    const float2 bg  = *(const float2*)((const char*)gates + ogt);

    const float dv = dxv.x, xv = dxv.y;
    const float betas = dv * bg.x;
    const float gam   = dv * bg.y;
    S += dv;

    // channel A (state index n)
    {
      const float mag = fexp2(dv * Are2a);
      const float rev = dv * AimRa;
      const float sn = fsin_rev(rev), co = fcos_rev(rev);
      const float are = mag * co, aim = mag * sn;
      const float bxr = xv * bca.x, bxi = xv * bca.y;
      const float tr = fmaf(betas, bxpra, hra);
      const float ti = fmaf(betas, bxpia, hia);
      hra = fmaf(are, tr, fmaf(-aim, ti, gam * bxr));
      hia = fmaf(are, ti, fmaf(aim, tr, gam * bxi));
      bxpra = bxr; bxpia = bxi;
    }
    // channel B (state index n+8)
    {
      const float mag = fexp2(dv * Are2b);
      const float rev = dv * AimRb;
      const float sn = fsin_rev(rev), co = fcos_rev(rev);
      const float are = mag * co, aim = mag * sn;
      const float bxr = xv * bcb.x, bxi = xv * bcb.y;
      const float tr = fmaf(betas, bxprb, hrb);
      const float ti = fmaf(betas, bxpib, hib);
      hrb = fmaf(are, tr, fmaf(-aim, ti, gam * bxr));
      hib = fmaf(are, ti, fmaf(aim, tr, gam * bxi));
      bxprb = bxr; bxpib = bxi;
    }

    float y = fmaf(hra, bca.z, hia * bca.w) + fmaf(hrb, bcb.z, hib * bcb.w);
    y += __shfl_xor(y, 1);   // butterfly: direction-free, stays in 8-group
    y += __shfl_xor(y, 2);
    y += __shfl_xor(y, 4);

    if (n == 0) {
      *(float*)((char*)pyd + opy)  = fmaf(Dc, xv, y);  // yd (ungated)
      *(float*)((char*)Ssum + oss) = S;
    }
    odx += 8192u; osc += 2048u; ogt += 64u; opy += 8192u; oss += 4096u;
  }
  const int sbase = (((b * 16 + ck) * 8 + h) << 11) + d * 16 + n;
  csum[sbase]     = make_float2(hra, hia);
  csum[sbase + 8] = make_float2(hrb, hib);
}

// ---------------------------------------------------------------------------
// part2: carry scan over 16 chunk summaries; A_chunk from S64 (shared-A
// cumulative-product identity).  Reads csum [.,d,n]; writes hstT TRANSPOSED
// [b,ck,h,n,d] so part3's per-n loads are lane-coalesced (R15 fix).
// ---------------------------------------------------------------------------
__global__ __launch_bounds__(256)
void scan_part2_k(const float* __restrict__ Ssum, const float* __restrict__ A_log,
                  const float* __restrict__ A_imag, const float2* __restrict__ csum,
                  float2* __restrict__ hstT) {
  const int gid = blockIdx.x * 256 + threadIdx.x;  // 32768 total
  const int low = gid & 2047;                      // d*16+n
  const int h   = (gid >> 11) & 7;
  const int b   = gid >> 14;
  const int n   = low & 15;
  const int dd  = low >> 4;
  const int c   = h * 128 + dd;
  const float Are2 = -__expf(A_log[h * 16 + n]) * 1.44269504f;
  const float AimR = A_imag[h * 16 + n] * 0.15915494f;
  float hr = 0.f, hi = 0.f;  // carry
#pragma unroll
  for (int ck = 0; ck < 16; ++ck) {
    const int base = ((b * 16 + ck) * 8 + h) << 11;
    const float2 he = csum[base + low];
    const float S64 = Ssum[(size_t)(b * 1024 + ck * 64 + 63) * 1024 + c];
    hstT[base + n * 128 + dd] = make_float2(hr, hi);  // transposed hstart
    const float mag = fexp2(S64 * Are2);
    const float rev = S64 * AimR;
    const float sn = fsin_rev(rev), co = fcos_rev(rev);
    const float ar = mag * co, ai = mag * sn;
    const float nhr = fmaf(ar, hr, fmaf(-ai, hi, he.x));
    const float nhi = fmaf(ar, hi, fmaf(ai, hr, he.y));
    hr = nhr; hi = nhi;
  }
}

// ---------------------------------------------------------------------------
// part3: one thread per output (t,c); inner n-loop over 16 states (full
// unroll; all loads independent and coalesced/broadcast).
//   corr = sum_n mag_n*(co_n*u_n + sn_n*v_n),  u=Cr*hcr+Ci*hci,
//   v=Ci*hcr-Cr*hci;  out[t,c] = (yd + corr) * gz.
// hc from hstT [b,ck,h,n,d]: lane c -> consecutive d -> one 512B
// transaction per n (R15's [.,d,n] layout was a 128B-stride scatter).
// ---------------------------------------------------------------------------
__global__ __launch_bounds__(256)
void scan_part3_k(const float* __restrict__ gz, const float* __restrict__ pyd,
                  const float* __restrict__ Ssum, const float4* __restrict__ scanin,
                  const float2* __restrict__ AA, const float2* __restrict__ hstT,
                  short* __restrict__ ygb) {
  const int gid = blockIdx.x * 256 + threadIdx.x;  // 2,097,152
  const int c  = gid & 1023;
  const int t  = gid >> 10;
  const int h  = c >> 7;
  const int d  = c & 127;
  const int b  = t >> 10;
  const int ck = (t >> 6) & 15;

  const float S   = Ssum[(size_t)t * 1024 + c];
  const float ydv = pyd[(size_t)t * 2048 + c];
  const float gzv = gz[(size_t)t * 2048 + 1024 + c];

  const float2* hc = hstT + ((((b * 16 + ck) * 8 + h) << 11) + d);  // + n*128
  const float2* cv = reinterpret_cast<const float2*>(scanin + (size_t)t * 128 + h * 16);
  const float2* aa = AA + h * 16;

  float corr = 0.f;
#pragma unroll
  for (int n = 0; n < 16; ++n) {
    const float2 a   = aa[n];
    const float2 hcv = hc[n * 128];       // coalesced: lanes = consecutive d
    const float2 cvv = cv[2 * n + 1];     // {Cr, Ci}, wave-broadcast
    const float mag = fexp2(S * a.x);
    const float rev = S * a.y;
    const float sn = fsin_rev(rev), co = fcos_rev(rev);
    const float u = fmaf(cvv.x, hcv.x, cvv.y * hcv.y);
    const float v = fmaf(cvv.y, hcv.x, -cvv.x * hcv.y);
    corr = fmaf(mag, fmaf(co, u, sn * v), corr);
  }
  ygb[(size_t)t * 1024 + c] = f2bf((ydv + corr) * gzv);
}

// ---------------------------------------------------------------------------
extern "C" void kernel_launch(void* const* d_in, const int* in_sizes, int n_in,
                              void* d_out, int out_size, void* d_ws, size_t ws_size,
                              hipStream_t stream) {
  (void)in_sizes; (void)n_in; (void)out_size; (void)ws_size;
  const float* x       = (const float*)d_in[0];
  const float* W_in    = (const float*)d_in[1];
  const float* conv_w  = (const float*)d_in[2];
  const float* conv_b  = (const float*)d_in[3];
  const float* W_x     = (const float*)d_in[4];
  const float* W_dt    = (const float*)d_in[5];
  const float* b_dt    = (const float*)d_in[6];
  const float* A_log   = (const float*)d_in[7];
  const float* A_imag  = (const float*)d_in[8];
  const float* D_param = (const float*)d_in[9];
  const float* W_out   = (const float*)d_in[10];
  float* out = (float*)d_out;

  // workspace layout (float offsets); total 16,154,880 floats = 61.6 MiB.
  // xz x-half (cols 0-1023) is dead after conv_silu -> part1 stores yd there.
  // csum stays read-only in part2; hstT is the transposed carry table.
  // Aliases live inside csum+Ssum's slot [11960320, 15106048); all are dead
  // before part1 writes csum/Ssum.  AA and hstT live past the scan -> own slots.
  //   x_bf   [11960320, 12484608)   1,048,576 shorts
  //   win_bf [12484608, 13008896)   1,048,576 shorts
  //   xc_bf  [13008896, 14057472)   2,097,152 shorts
  //   wx_bf  [14057472, 14344192)     573,440 shorts
  //   wdtT   [14344192, 14376960)      32,768 floats
  //   AA     [15106048, 15106304)     128 float2 (not aliased)
  //   hstT   [15106304, 16154880)     512K float2 (not aliased)
  float* ws = (float*)d_ws;
  float*  xz      = ws;                          // 4,194,304 (yd aliases x-half)
  float*  proj    = ws + 4194304;                // 1,146,880
  float2* dx      = (float2*)(ws + 5341184);     // 4,194,304 (2M float2)
  float4* scanin  = (float4*)(ws + 9535488);     // 1,048,576
  float2* gates   = (float2*)(ws + 10584064);    //    65,536
  short*  yg_bf   = (short*)(ws + 10649600);     // 1,048,576 (2M shorts)
  short*  wout_bf = (short*)(ws + 11698176);     //   262,144
  float2* csum    = (float2*)(ws + 11960320);    // 1,048,576 (512K float2)
  float*  Ssum    = ws + 13008896;               // 2,097,152
  short*  x_bf    = (short*)(ws + 11960320);     //   [alias, see map]
  short*  win_bf  = (short*)(ws + 12484608);     //   [alias]
  short*  xc_bf   = (short*)(ws + 13008896);     //   [alias]
  short*  wx_bf   = (short*)(ws + 14057472);     //   [alias]
  float*  wdtT    = ws + 14344192;               //   [alias]
  float2* AA      = (float2*)(ws + 15106048);    //   durable
  float2* hstT    = (float2*)(ws + 15106304);    //   durable (4 MB)

  // 0) conversions + W_dt transpose + AA table (one kernel)
  cvt_all_k<<<dim3(3249), dim3(256), 0, stream>>>(x, W_in, W_x, W_out, W_dt,
                                                  A_log, A_imag,
                                                  x_bf, win_bf, wx_bf, wout_bf,
                                                  wdtT, AA);
  // 1) xz = x @ W_in^T        (M=2048, N=2048, K=512)
  gemm_bf16_128<<<dim3(16, 16), dim3(256), 0, stream>>>(x_bf, win_bf, xz, 2048, 512);
  // 2) dx.y = silu(dwconv(x_proj)) (+ bf16 copy); in-place silu on z half
  conv_silu_k<<<dim3(8192), dim3(256), 0, stream>>>(xz, conv_w, conv_b,
                                                    (float*)dx, xc_bf);
  // 3) proj = xc @ W_x^T      (M=2048, N=560, K=1024)
  gemm_bf16_64<<<dim3(9, 32), dim3(256), 0, stream>>>(xc_bf, wx_bf, proj, 560, 1024);
  // 4) dx.x = delta; scanin/gates pack
  pack2_k<<<dim3(9216), dim3(256), 0, stream>>>(proj, wdtT, b_dt, (float*)dx,
                                                scanin, gates);
  // 5) split-carry scan
  scan_part1_k<<<dim3(1024), dim3(256), 0, stream>>>(xz, dx, scanin, gates,
                                                     A_log, A_imag, D_param,
                                                     Ssum, csum);
  scan_part2_k<<<dim3(128), dim3(256), 0, stream>>>(Ssum, A_log, A_imag, csum,
                                                    hstT);
  scan_part3_k<<<dim3(8192), dim3(256), 0, stream>>>(xz, xz, Ssum, scanin,
                                                     AA, hstT, yg_bf);
  // 6) out = yg_bf @ W_out^T  (M=2048, N=512, K=1024)
  gemm_bf16_64<<<dim3(8, 32), dim3(256), 0, stream>>>(yg_bf, wout_bf, out, 512, 1024);
}